// Round 7
// baseline (177.310 us; speedup 1.0000x reference)
//
#include <hip/hip_runtime.h>
#include <hip/hip_bf16.h>
#include <cstdint>

typedef __bf16 bf16;
typedef bf16 bf16x8 __attribute__((ext_vector_type(8)));
typedef float f32x4 __attribute__((ext_vector_type(4)));

#define NTOK 4096   // B*T
#define DLBL 512    // D_LABEL
#define NLAB 50

__device__ inline bf16x8 cvt8(float4 a, float4 b) {
  bf16x8 r;
  r[0] = (bf16)a.x; r[1] = (bf16)a.y; r[2] = (bf16)a.z; r[3] = (bf16)a.w;
  r[4] = (bf16)b.x; r[5] = (bf16)b.y; r[6] = (bf16)b.z; r[7] = (bf16)b.w;
  return r;
}

// async global->LDS, 16B per lane; LDS dest = wave-uniform base + lane*16
__device__ __forceinline__ void gl16(const bf16* g, void* l) {
  __builtin_amdgcn_global_load_lds(
      (const __attribute__((address_space(1))) void*)g,
      (__attribute__((address_space(3))) void*)l, 16, 0, 0);
}

// ---------------------------------------------------------------------------
// Fused prep kernel: blocks [0,256) projA, [256,512) projB, [512,6912) convW.
// ---------------------------------------------------------------------------
__device__ void projA_body(int bidx, const float* __restrict__ Wp,
                           const float* __restrict__ X,
                           const float* __restrict__ bv,
                           bf16* __restrict__ outT, char* lds) {
  char* ldsA = lds;           // [128 e][32 d] bf16, row stride 80B
  char* ldsB = lds + 10240;   // [64 tok][32 d] bf16, row stride 80B
  const int tid = threadIdx.x, l = tid & 63, w = tid >> 6;
  const int tokbase = (bidx >> 2) * 64;
  const int ebase   = (bidx & 3) * 128;
  const int wr = w & 1, wc = w >> 1;
  f32x4 acc[4][2] = {};
  const int arow = tid >> 1, ahalf = tid & 1;
  const int brow = tid >> 2, bgr = tid & 3;
  const float* aS = Wp + (size_t)(ebase + arow) * 1024 + ahalf * 16;
  const float* bS = X  + (size_t)(tokbase + brow) * 1024 + bgr * 8;
  const int lo = (l & 15) * 80 + (l >> 4) * 16;
  for (int kb = 0; kb < 1024; kb += 32) {
    float4 a0 = *(const float4*)(aS + kb);
    float4 a1 = *(const float4*)(aS + kb + 4);
    float4 a2 = *(const float4*)(aS + kb + 8);
    float4 a3 = *(const float4*)(aS + kb + 12);
    float4 b0 = *(const float4*)(bS + kb);
    float4 b1 = *(const float4*)(bS + kb + 4);
    *(bf16x8*)(ldsA + arow * 80 + ahalf * 32)      = cvt8(a0, a1);
    *(bf16x8*)(ldsA + arow * 80 + ahalf * 32 + 16) = cvt8(a2, a3);
    *(bf16x8*)(ldsB + brow * 80 + bgr * 16)        = cvt8(b0, b1);
    __syncthreads();
    bf16x8 aF[4], bF[2];
#pragma unroll
    for (int i = 0; i < 4; ++i) aF[i] = *(bf16x8*)(ldsA + (wr * 64 + i * 16) * 80 + lo);
#pragma unroll
    for (int j = 0; j < 2; ++j) bF[j] = *(bf16x8*)(ldsB + (wc * 32 + j * 16) * 80 + lo);
#pragma unroll
    for (int i = 0; i < 4; ++i)
#pragma unroll
      for (int j = 0; j < 2; ++j)
        acc[i][j] = __builtin_amdgcn_mfma_f32_16x16x32_bf16(aF[i], bF[j], acc[i][j], 0, 0, 0);
    __syncthreads();
  }
#pragma unroll
  for (int i = 0; i < 4; ++i)
#pragma unroll
    for (int j = 0; j < 2; ++j)
#pragma unroll
      for (int r = 0; r < 4; ++r) {
        int eg = ebase + wr * 64 + i * 16 + (l >> 4) * 4 + r;
        int tg = tokbase + wc * 32 + j * 16 + (l & 15);
        outT[(size_t)eg * NTOK + tg] = (bf16)(acc[i][j][r] + bv[eg]);
      }
}

__device__ void projB_body(int bidx, const float* __restrict__ head,
                           const int* __restrict__ hidx,
                           const float* __restrict__ Wp,
                           const float* __restrict__ bv,
                           bf16* __restrict__ selO, char* lds) {
  char* ldsA = lds;           // [128 tok][32 d], stride 80
  char* ldsB = lds + 10240;   // [64 e][32 d], stride 80
  const int tid = threadIdx.x, l = tid & 63, w = tid >> 6;
  const int tokbase = (bidx >> 3) * 128;
  const int ebase   = (bidx & 7) * 64;
  const int wr = w & 1, wc = w >> 1;
  f32x4 acc[4][2] = {};
  const int arow = tid >> 1, ahalf = tid & 1;
  const int brow = tid >> 2, bgr = tid & 3;
  const int flat = tokbase + arow;
  const int bb = flat >> 11;
  const int hv = hidx[flat];
  const float* aS = head + ((size_t)bb * 2049 + hv) * 1024 + ahalf * 16;
  const float* bS = Wp + (size_t)(ebase + brow) * 1024 + bgr * 8;
  const int lo = (l & 15) * 80 + (l >> 4) * 16;
  for (int kb = 0; kb < 1024; kb += 32) {
    float4 a0 = *(const float4*)(aS + kb);
    float4 a1 = *(const float4*)(aS + kb + 4);
    float4 a2 = *(const float4*)(aS + kb + 8);
    float4 a3 = *(const float4*)(aS + kb + 12);
    float4 b0 = *(const float4*)(bS + kb);
    float4 b1 = *(const float4*)(bS + kb + 4);
    *(bf16x8*)(ldsA + arow * 80 + ahalf * 32)      = cvt8(a0, a1);
    *(bf16x8*)(ldsA + arow * 80 + ahalf * 32 + 16) = cvt8(a2, a3);
    *(bf16x8*)(ldsB + brow * 80 + bgr * 16)        = cvt8(b0, b1);
    __syncthreads();
    bf16x8 aF[4], bF[2];
#pragma unroll
    for (int i = 0; i < 4; ++i) aF[i] = *(bf16x8*)(ldsA + (wr * 64 + i * 16) * 80 + lo);
#pragma unroll
    for (int j = 0; j < 2; ++j) bF[j] = *(bf16x8*)(ldsB + (wc * 32 + j * 16) * 80 + lo);
#pragma unroll
    for (int i = 0; i < 4; ++i)
#pragma unroll
      for (int j = 0; j < 2; ++j)
        acc[i][j] = __builtin_amdgcn_mfma_f32_16x16x32_bf16(aF[i], bF[j], acc[i][j], 0, 0, 0);
    __syncthreads();
  }
#pragma unroll
  for (int i = 0; i < 4; ++i)
#pragma unroll
    for (int j = 0; j < 2; ++j)
#pragma unroll
      for (int r = 0; r < 4; ++r) {
        int tg = tokbase + wr * 64 + i * 16 + (l >> 4) * 4 + r;
        int eg = ebase + wc * 32 + j * 16 + (l & 15);
        selO[(size_t)tg * DLBL + eg] = (bf16)(acc[i][j][r] + bv[eg]);
      }
}

__global__ __launch_bounds__(256) void prep_k(const float* __restrict__ W,
                                              bf16* __restrict__ Wb,
                                              const float* __restrict__ dep_W,
                                              const float* __restrict__ dep,
                                              const float* __restrict__ dep_b,
                                              bf16* __restrict__ depT,
                                              const float* __restrict__ head,
                                              const int* __restrict__ hidx,
                                              const float* __restrict__ head_W,
                                              const float* __restrict__ head_b,
                                              bf16* __restrict__ selB) {
  __shared__ char lds[15360];
  const int b = blockIdx.x;
  if (b < 256) {
    projA_body(b, dep_W, dep, dep_b, depT, lds);
  } else if (b < 512) {
    projB_body(b - 256, head, hidx, head_W, head_b, selB, lds);
  } else {
    int i = (b - 512) * 256 + threadIdx.x;
    const float4* s = (const float4*)W + (size_t)i * 2;
    float4 a = s[0], c = s[1];
    *(bf16x8*)(Wb + (size_t)i * 8) = cvt8(a, c);
  }
}

// ---------------------------------------------------------------------------
// Kernel 4 v7: biaffine GEMM, m201-style 4-phase/K-tile schedule (T2+T3+T4+T5).
//   Tile 256d x 256tok, BK=64 = 2 x kk32, K=512 -> 8 K-tiles.
//   8 waves (2d x 4tok); wave tile 128d x 64tok = 8x4 frags.
//   LDS 128KB = 2 buf x {A-kk0, B-kk0, A-kk1, B-kk1} 16KB regions.
//   Phase p of tile t: {4-8 ds_read || stage unit p of tile t+1 (2 gl16) ->
//     barrier -> 16 MFMA (setprio) -> barrier}; vmcnt(4) before the barrier
//     at ph1 & ph3 only (3-phase load lead, never drained mid-loop).
//   Unit order: ph0->A-kk0, ph1->B-kk0, ph2->A-kk1, ph3->B-kk1.
//   Certification: t.ph1-end vmcnt(4) certifies kk1-units of t (issued
//   t-1.ph2/ph3); t.ph3-end vmcnt(4) certifies kk0-units of t+1. Buffer
//   (t+1)&1 freed by t-1's closing barrier before any t.phX stage issue.
//   XCD pairs: 2 XCDs share 25 combos (combo-fast, tok-slow) -> W panel
//   and sel tile L2-resident (r5/r6-proven ordering).
// ---------------------------------------------------------------------------
__global__ __launch_bounds__(512, 2) void biaff_k(const bf16* __restrict__ Wb,
                                                  const bf16* __restrict__ sel,
                                                  const bf16* __restrict__ depT,
                                                  float* __restrict__ parts) {
  __shared__ char lds[131072];
  const int tid = threadIdx.x, l = tid & 63, w = tid >> 6;   // w 0..7

  // XCD-pair decode: 1600 = 8 xcd * 200; pair g=xcd>>1 owns 25 combos.
  const int lin = blockIdx.x;
  const int xcd = lin & 7, j5 = lin >> 3;      // j5 0..199
  const int g = xcd >> 1, h = xcd & 1;
  const int combo = g * 25 + (j5 % 25);        // 0..99, combo-fast
  const int bx = (j5 / 25) * 2 + h;            // 0..15
  const int n  = combo % 50;
  const int dz = combo / 50;                   // 0..1
  const int tokbase = bx * 256;

  const int wd = w >> 2, wt = w & 3;           // wave tile: 128 d x 64 tok
  f32x4 acc[8][4] = {};

  // staging: lane -> row l>>2 (of 16), chunk l&3; source chunk pre-swizzled
  // so LDS image carries chunk ^= ((row>>1)&3). Wave w covers rows w*32..+32
  // of each 256-row region via 2 gl16.
  const int srow = l >> 2;
  const int schunk = ((l & 3) ^ ((l >> 3) & 3)) * 8;
  const bf16* aG = Wb  + ((size_t)(n * DLBL + dz * 256 + w * 32 + srow)) * DLBL + schunk;
  const bf16* bG = sel + ((size_t)(tokbase + w * 32 + srow)) * DLBL + schunk;
  const int aOff = w * 2048;                   // (w*32 rows)*64B within region

  // frag reads: row stride 64B, chunk = lh ^ ((lq>>1)&3)  (conflict-free r5/r6)
  const int lq = l & 15, lh = l >> 4;
  const int ro = lh ^ ((lq >> 1) & 3);
  const char* rdA = lds + (wd * 128 + lq) * 64 + ro * 16;          // + M*4096 + i*1024
  const char* rdB = lds + 16384 + (wt * 64 + lq) * 64 + ro * 16;   // + j*1024

#define STG_A(T, KK) do { \
    const bf16* s_ = aG + (T) * 64 + (KK) * 32; \
    char* d_ = lds + (((T) & 1) * 65536) + (KK) * 32768 + aOff; \
    gl16(s_, d_); gl16(s_ + 16 * DLBL, d_ + 1024); \
  } while (0)
#define STG_B(T, KK) do { \
    const bf16* s_ = bG + (T) * 64 + (KK) * 32; \
    char* d_ = lds + (((T) & 1) * 65536) + 16384 + (KK) * 32768 + aOff; \
    gl16(s_, d_); gl16(s_ + 16 * DLBL, d_ + 1024); \
  } while (0)
#define WAITV(N) asm volatile("s_waitcnt vmcnt(" #N ")" ::: "memory")
#define RDA(KK, M) do { _Pragma("unroll") for (int i = 0; i < 4; ++i) \
    aF[i] = *(const bf16x8*)(rdA + cb + (KK) * 32768 + (M) * 4096 + i * 1024); } while (0)
#define RDB(KK) do { _Pragma("unroll") for (int jj = 0; jj < 4; ++jj) \
    bF[jj] = *(const bf16x8*)(rdB + cb + (KK) * 32768 + jj * 1024); } while (0)
#define MM(M) do { \
    __builtin_amdgcn_s_setprio(1); \
    _Pragma("unroll") for (int i = 0; i < 4; ++i) \
      _Pragma("unroll") for (int jj = 0; jj < 4; ++jj) \
        acc[(M) * 4 + i][jj] = __builtin_amdgcn_mfma_f32_16x16x32_bf16(aF[i], bF[jj], acc[(M) * 4 + i][jj], 0, 0, 0); \
    __builtin_amdgcn_s_setprio(0); \
  } while (0)
#define BAR __builtin_amdgcn_s_barrier()

#define TILE(T, DOSTG, V1, DOV3) do { \
    const int cb = ((T) & 1) * 65536; \
    bf16x8 aF[4], bF[4]; \
    /* ph0: kk0, m0-3 */ \
    RDA(0, 0); RDB(0); \
    if (DOSTG) STG_A((T) + 1, 0); \
    BAR; MM(0); BAR; \
    /* ph1: kk0, m4-7 (bF reused) */ \
    RDA(0, 1); \
    if (DOSTG) STG_B((T) + 1, 0); \
    BAR; MM(1); WAITV(V1); BAR; \
    /* ph2: kk1, m0-3 */ \
    RDA(1, 0); RDB(1); \
    if (DOSTG) STG_A((T) + 1, 1); \
    BAR; MM(0); BAR; \
    /* ph3: kk1, m4-7 */ \
    RDA(1, 1); \
    if (DOSTG) STG_B((T) + 1, 1); \
    BAR; MM(1); \
    if (DOV3) { WAITV(4); } \
    if (DOV3) { BAR; } \
  } while (0)

  // prologue: stage all 4 units of tile 0 (8 loads/wave); drain; barrier
  STG_A(0, 0); STG_B(0, 0); STG_A(0, 1); STG_B(0, 1);
  WAITV(0);
  BAR;

  TILE(0, 1, 4, 1);
  TILE(1, 1, 4, 1);
  TILE(2, 1, 4, 1);
  TILE(3, 1, 4, 1);
  TILE(4, 1, 4, 1);
  TILE(5, 1, 4, 1);
  TILE(6, 1, 4, 1);
  TILE(7, 0, 0, 0);   // last: certify kk1 with full drain at ph1; no trailing sync

#undef TILE
#undef BAR
#undef MM
#undef RDB
#undef RDA
#undef WAITV
#undef STG_B
#undef STG_A

  // ---- epilogue: H[d,t] * depT[d,t], reduce over the wave's 128 d ----
  const bf16* dT = depT + (size_t)(dz * 256 + wd * 128) * NTOK;
  float p[4] = {0.f, 0.f, 0.f, 0.f};
#pragma unroll
  for (int jj = 0; jj < 4; ++jj) {
    const int tg = tokbase + wt * 64 + jj * 16 + lq;
#pragma unroll
    for (int i = 0; i < 8; ++i)
#pragma unroll
      for (int r = 0; r < 4; ++r)
        p[jj] += acc[i][jj][r] * (float)dT[(size_t)(i * 16 + lh * 4 + r) * NTOK + tg];
  }
#pragma unroll
  for (int jj = 0; jj < 4; ++jj) {
    p[jj] += __shfl_xor(p[jj], 16);
    p[jj] += __shfl_xor(p[jj], 32);
  }
  if (l < 16) {
#pragma unroll
    for (int jj = 0; jj < 4; ++jj) {
      int tg = tokbase + wt * 64 + jj * 16 + l;
      parts[(size_t)(dz * 2 + wd) * 204800 + (size_t)tg * NLAB + n] = p[jj];
    }
  }
}

// ---------------------------------------------------------------------------
// Kernel 5: sum the 4 d-partials + bias -> logits [4096][50] f32
// ---------------------------------------------------------------------------
__global__ __launch_bounds__(256) void fin_k(const float* __restrict__ parts,
                                             const float* __restrict__ bias,
                                             float* __restrict__ out) {
  int i = blockIdx.x * 256 + threadIdx.x;
  float v = 0.f;
#pragma unroll
  for (int q = 0; q < 4; ++q) v += parts[(size_t)q * 204800 + i];
  out[i] = v + bias[i % NLAB];
}

// ---------------------------------------------------------------------------
extern "C" void kernel_launch(void* const* d_in, const int* in_sizes, int n_in,
                              void* d_out, int out_size, void* d_ws, size_t ws_size,
                              hipStream_t stream) {
  const float* dep    = (const float*)d_in[0];
  const float* head   = (const float*)d_in[1];
  const int*   hidx   = (const int*)d_in[2];
  const float* dep_W  = (const float*)d_in[4];
  const float* dep_b  = (const float*)d_in[5];
  const float* head_W = (const float*)d_in[6];
  const float* head_b = (const float*)d_in[7];
  const float* W      = (const float*)d_in[8];
  const float* bias   = (const float*)d_in[9];
  float* out = (float*)d_out;

  char* ws = (char*)d_ws;
  bf16*  Wb    = (bf16*)(ws);
  bf16*  depT  = (bf16*)(ws + 26214400);
  bf16*  selB  = (bf16*)(ws + 30408704);
  float* parts = (float*)(ws + 34603008);
  if (ws_size < (size_t)37879808) return;

  hipLaunchKernelGGL(prep_k, dim3(6912), dim3(256), 0, stream,
                     W, Wb, dep_W, dep, dep_b, depT, head, hidx, head_W, head_b, selB);
  hipLaunchKernelGGL(biaff_k, dim3(1600), dim3(512), 0, stream, Wb, selB, depT, parts);
  hipLaunchKernelGGL(fin_k, dim3(800), dim3(256), 0, stream, parts, bias, out);
}